// Round 1
// baseline (264.473 us; speedup 1.0000x reference)
//
#include <hip/hip_runtime.h>
#include <hip/hip_bf16.h>

#define VNUM 6890
#define BNUM 512
#define NJ 24

// ws layout (floats):
//   js  [24*33]           = 792         (JS[j,c,s] s<10, JT at s=10)
//   lw  [512*207]         = 105984      (lrotmin)
//   gp  [512*24*12]       = 147456      (G' 3x4 row-major per (b,j))
#define WS_JS 0
#define WS_LW 792
#define WS_GP (792 + 512*207)

#define RES_ELEMS (512*6890*3)

// ---------------- Kernel A: JS/JT = reduce_v Jr[j,v] * {shapedirs, v_template}
__global__ __launch_bounds__(256) void ka_kernel(const float* __restrict__ Jr,
                                                 const float* __restrict__ sd,
                                                 const float* __restrict__ vt,
                                                 float* __restrict__ js) {
    int j = blockIdx.x;
    int tid = threadIdx.x;
    float acc[33];
#pragma unroll
    for (int k = 0; k < 33; ++k) acc[k] = 0.f;
    for (int v = tid; v < VNUM; v += 256) {
        float q = Jr[j * VNUM + v];
#pragma unroll
        for (int c = 0; c < 3; ++c) {
#pragma unroll
            for (int s = 0; s < 10; ++s)
                acc[c * 11 + s] += q * sd[v * 30 + c * 10 + s];
            acc[c * 11 + 10] += q * vt[v * 3 + c];
        }
    }
#pragma unroll
    for (int k = 0; k < 33; ++k) {
        float a = acc[k];
#pragma unroll
        for (int off = 32; off >= 1; off >>= 1) a += __shfl_xor(a, off);
        acc[k] = a;
    }
    __shared__ float red[4][33];
    int lane = tid & 63, wid = tid >> 6;
    if (lane == 0) {
#pragma unroll
        for (int k = 0; k < 33; ++k) red[wid][k] = acc[k];
    }
    __syncthreads();
    if (tid < 33)
        js[j * 33 + tid] = red[0][tid] + red[1][tid] + red[2][tid] + red[3][tid];
}

// ---------------- Kernel B: per-batch rodrigues, lrotmin, J, kinematic chain, G'
__global__ __launch_bounds__(64) void kb_kernel(const float* __restrict__ pose,
                                                const float* __restrict__ betas,
                                                const float* __restrict__ js,
                                                float* __restrict__ lw,
                                                float* __restrict__ gp) {
    int b = blockIdx.x;
    int t = threadIdx.x;
    __shared__ float Rl[24][9];
    __shared__ float Jl[24][3];
    __shared__ float Gl[24][12];

    if (t < 24) {
        float x = pose[b * 72 + t * 3 + 0];
        float y = pose[b * 72 + t * 3 + 1];
        float z = pose[b * 72 + t * 3 + 2];
        float th = sqrtf(x * x + y * y + z * z) + 1e-8f;
        float rx = x / th, ry = y / th, rz = z / th;
        float cs = cosf(th), sn = sinf(th), mc = 1.f - cs;
        float R[9];
        R[0] = cs + mc * rx * rx;      R[1] = mc * rx * ry - sn * rz; R[2] = mc * rx * rz + sn * ry;
        R[3] = mc * ry * rx + sn * rz; R[4] = cs + mc * ry * ry;      R[5] = mc * ry * rz - sn * rx;
        R[6] = mc * rz * rx - sn * ry; R[7] = mc * rz * ry + sn * rx; R[8] = cs + mc * rz * rz;
#pragma unroll
        for (int k = 0; k < 9; ++k) Rl[t][k] = R[k];
        if (t >= 1) {
#pragma unroll
            for (int k = 0; k < 9; ++k)
                lw[(size_t)b * 207 + (t - 1) * 9 + k] = R[k] - ((k == 0 || k == 4 || k == 8) ? 1.f : 0.f);
        }
#pragma unroll
        for (int c = 0; c < 3; ++c) {
            float a = js[(t * 3 + c) * 11 + 10];
#pragma unroll
            for (int s = 0; s < 10; ++s) a += betas[b * 10 + s] * js[(t * 3 + c) * 11 + s];
            Jl[t][c] = a;
        }
    }
    __syncthreads();

    if (t < 12) {
        int x = t >> 2, yy = t & 3;
        Gl[0][t] = (yy < 3) ? Rl[0][x * 3 + yy] : Jl[0][x];
    }
    __syncthreads();

    const int par[24] = {-1, 0, 0, 0, 1, 2, 3, 4, 5, 6, 7, 8, 9, 9, 9, 12, 13, 14, 16, 17, 18, 19, 20, 21};
#pragma unroll
    for (int i = 1; i < 24; ++i) {
        if (t < 12) {
            int x = t >> 2, yy = t & 3;
            int p = par[i];
            float a0, a1, a2, add;
            if (yy < 3) {
                a0 = Rl[i][0 * 3 + yy]; a1 = Rl[i][1 * 3 + yy]; a2 = Rl[i][2 * 3 + yy]; add = 0.f;
            } else {
                a0 = Jl[i][0] - Jl[p][0]; a1 = Jl[i][1] - Jl[p][1]; a2 = Jl[i][2] - Jl[p][2];
                add = Gl[p][x * 4 + 3];
            }
            Gl[i][t] = Gl[p][x * 4 + 0] * a0 + Gl[p][x * 4 + 1] * a1 + Gl[p][x * 4 + 2] * a2 + add;
        }
        __syncthreads();
    }

    if (t < 24) {
#pragma unroll
        for (int x = 0; x < 3; ++x) {
            float tx = Gl[t][x * 4 + 0] * Jl[t][0] + Gl[t][x * 4 + 1] * Jl[t][1] + Gl[t][x * 4 + 2] * Jl[t][2];
#pragma unroll
            for (int yy = 0; yy < 3; ++yy)
                gp[(size_t)b * 288 + t * 12 + x * 4 + yy] = Gl[t][x * 4 + yy];
            gp[(size_t)b * 288 + t * 12 + x * 4 + 3] = Gl[t][x * 4 + 3] - tx;
        }
    }
}

// ---------------- Kernel C: fused shape-blend + pose-blend + skinning
// grid (108, 16), block 256. lane = vertex within 64-tile; wave handles 8 batches.
__global__ __launch_bounds__(256) void kc_kernel(const float* __restrict__ posedirs,
                                                 const float* __restrict__ lw,
                                                 const float* __restrict__ gpb,
                                                 const float* __restrict__ betas,
                                                 const float* __restrict__ sdirs,
                                                 const float* __restrict__ vt,
                                                 const float* __restrict__ trans,
                                                 const float* __restrict__ wgts,
                                                 float* __restrict__ out) {
    __shared__ float chunkL[64 * 99];  // [vloc][c*32+p], stride 99 -> conflict-free
    __shared__ float wl[64 * 25];      // weights, stride 25 -> conflict-free

    int tid = threadIdx.x;
    int lane = tid & 63;
    int wid = __builtin_amdgcn_readfirstlane(tid >> 6);
    int v0 = blockIdx.x * 64;
    int v = v0 + lane;
    int vc = min(v, VNUM - 1);
    int b0 = blockIdx.y * 32 + wid * 8;

    // stage weights tile (coalesced-ish, once)
    for (int t = tid; t < 64 * 24; t += 256) {
        int vv = t / 24, j = t - vv * 24;
        wl[vv * 25 + j] = wgts[(size_t)min(v0 + vv, VNUM - 1) * 24 + j];
    }

    // per-lane v_template and shapedirs
    float vtl[3];
#pragma unroll
    for (int c = 0; c < 3; ++c) vtl[c] = vt[vc * 3 + c];
    float sdl[30];
#pragma unroll
    for (int k = 0; k < 30; ++k) sdl[k] = sdirs[vc * 30 + k];

    // init accumulators with v_shaped (betas are scalar loads: b uniform per wave)
    float acc[8][3];
#pragma unroll
    for (int i = 0; i < 8; ++i) {
#pragma unroll
        for (int c = 0; c < 3; ++c) {
            float a = vtl[c];
#pragma unroll
            for (int s = 0; s < 10; ++s) a += betas[(b0 + i) * 10 + s] * sdl[c * 10 + s];
            acc[i][c] = a;
        }
    }

    // chunked pose-blend: 7 chunks of 32 p (207 total, guarded)
    float pref[6][4];
    // prefetch chunk 0
    {
        int pc = 0;
#pragma unroll
        for (int pass = 0; pass < 6; ++pass) {
            int idx = pass * 256 + tid;
            int vloc = idx / 24;
            int cp = idx - vloc * 24;
            int c = cp >> 3, p4 = cp & 7;
            int p = pc + p4 * 4;
            const float* s = posedirs + (size_t)min(v0 + vloc, VNUM - 1) * 621 + c * 207 + p;
#pragma unroll
            for (int k = 0; k < 4; ++k) pref[pass][k] = (p + k < 207) ? s[k] : 0.f;
        }
    }

    for (int ch = 0; ch < 7; ++ch) {
        // write prefetched chunk to LDS
#pragma unroll
        for (int pass = 0; pass < 6; ++pass) {
            int idx = pass * 256 + tid;
            int vloc = idx / 24;
            int cp = idx - vloc * 24;
            int c = cp >> 3, p4 = cp & 7;
            int base = vloc * 99 + c * 32 + p4 * 4;
#pragma unroll
            for (int k = 0; k < 4; ++k) chunkL[base + k] = pref[pass][k];
        }
        __syncthreads();
        // prefetch next chunk (overlaps with compute below)
        if (ch < 6) {
            int pc = (ch + 1) * 32;
#pragma unroll
            for (int pass = 0; pass < 6; ++pass) {
                int idx = pass * 256 + tid;
                int vloc = idx / 24;
                int cp = idx - vloc * 24;
                int c = cp >> 3, p4 = cp & 7;
                int p = pc + p4 * 4;
                const float* s = posedirs + (size_t)min(v0 + vloc, VNUM - 1) * 621 + c * 207 + p;
#pragma unroll
                for (int k = 0; k < 4; ++k) pref[pass][k] = (p + k < 207) ? s[k] : 0.f;
            }
        }
        int pc = ch * 32;
        for (int p = 0; p < 32; ++p) {
            int pg = pc + p;
            if (pg >= 207) break;  // uniform
            float e0 = chunkL[lane * 99 + p];
            float e1 = chunkL[lane * 99 + 32 + p];
            float e2 = chunkL[lane * 99 + 64 + p];
#pragma unroll
            for (int i = 0; i < 8; ++i) {
                float lr = lw[(size_t)(b0 + i) * 207 + pg];  // scalar load
                acc[i][0] += lr * e0;
                acc[i][1] += lr * e1;
                acc[i][2] += lr * e2;
            }
        }
        __syncthreads();
    }

    // skinning: T = sum_j w[v,j] * G'[b,j], out = T.[vp,1] + trans
#pragma unroll
    for (int i = 0; i < 8; ++i) {
        int b = b0 + i;
        const float* g = gpb + (size_t)b * 288;
        float T[12];
#pragma unroll
        for (int r = 0; r < 12; ++r) T[r] = 0.f;
#pragma unroll 4
        for (int j = 0; j < 24; ++j) {
            float wg = wl[lane * 25 + j];
#pragma unroll
            for (int r = 0; r < 12; ++r) T[r] += wg * g[j * 12 + r];  // g scalar loads
        }
        float vx = acc[i][0], vy = acc[i][1], vz = acc[i][2];
        float o0 = T[0] * vx + T[1] * vy + T[2] * vz + T[3] + trans[b * 3 + 0];
        float o1 = T[4] * vx + T[5] * vy + T[6] * vz + T[7] + trans[b * 3 + 1];
        float o2 = T[8] * vx + T[9] * vy + T[10] * vz + T[11] + trans[b * 3 + 2];
        if (v < VNUM) {
            float* o = out + ((size_t)b * VNUM + v) * 3;
            o[0] = o0; o[1] = o1; o[2] = o2;
        }
    }
}

// ---------------- Kernel D: joints[b,j,c] = sum_v jr2[j,v] * result[b,v,c]
__global__ __launch_bounds__(256) void kd_kernel(const float* __restrict__ res,
                                                 const float* __restrict__ jr2,
                                                 float* __restrict__ joints) {
    int b = blockIdx.x;
    int tid = threadIdx.x;
    float acc[24][3];
#pragma unroll
    for (int j = 0; j < 24; ++j)
#pragma unroll
        for (int c = 0; c < 3; ++c) acc[j][c] = 0.f;

    const float* rb = res + (size_t)b * VNUM * 3;
    for (int v = tid; v < VNUM; v += 256) {
        float r0 = rb[v * 3 + 0];
        float r1 = rb[v * 3 + 1];
        float r2 = rb[v * 3 + 2];
#pragma unroll
        for (int j = 0; j < 24; ++j) {
            float q = jr2[(size_t)j * VNUM + v];
            acc[j][0] += q * r0;
            acc[j][1] += q * r1;
            acc[j][2] += q * r2;
        }
    }
#pragma unroll
    for (int j = 0; j < 24; ++j)
#pragma unroll
        for (int c = 0; c < 3; ++c) {
            float a = acc[j][c];
#pragma unroll
            for (int off = 32; off >= 1; off >>= 1) a += __shfl_xor(a, off);
            acc[j][c] = a;
        }
    __shared__ float red[4][72];
    int lane = tid & 63, wid = tid >> 6;
    if (lane == 0) {
#pragma unroll
        for (int j = 0; j < 24; ++j)
#pragma unroll
            for (int c = 0; c < 3; ++c) red[wid][j * 3 + c] = acc[j][c];
    }
    __syncthreads();
    if (tid < 72)
        joints[(size_t)b * 72 + tid] = red[0][tid] + red[1][tid] + red[2][tid] + red[3][tid];
}

extern "C" void kernel_launch(void* const* d_in, const int* in_sizes, int n_in,
                              void* d_out, int out_size, void* d_ws, size_t ws_size,
                              hipStream_t stream) {
    const float* betas = (const float*)d_in[0];
    const float* pose = (const float*)d_in[1];
    const float* trans = (const float*)d_in[2];
    const float* v_template = (const float*)d_in[3];
    const float* shapedirs = (const float*)d_in[4];
    const float* posedirs = (const float*)d_in[5];
    const float* J_regressor = (const float*)d_in[6];
    const float* joint_regressor = (const float*)d_in[7];
    const float* weights = (const float*)d_in[8];
    float* out = (float*)d_out;

    float* wsf = (float*)d_ws;  // needs ~1.02 MB
    float* js = wsf + WS_JS;
    float* lw = wsf + WS_LW;
    float* gp = wsf + WS_GP;

    ka_kernel<<<24, 256, 0, stream>>>(J_regressor, shapedirs, v_template, js);
    kb_kernel<<<512, 64, 0, stream>>>(pose, betas, js, lw, gp);
    kc_kernel<<<dim3(108, 16), 256, 0, stream>>>(posedirs, lw, gp, betas, shapedirs,
                                                 v_template, trans, weights, out);
    kd_kernel<<<512, 256, 0, stream>>>(out, joint_regressor, out + RES_ELEMS);
}